// Round 4
// baseline (277.521 us; speedup 1.0000x reference)
//
#include <hip/hip_runtime.h>
#include <hip/hip_bf16.h>

// Word2Vec NCE loss:
//   B=16384 batch, C=10 context, K=5 negatives/context, V=400000, D=300 (fp32)
// loss = -mean_b[ mean_c logsig(ctx_bc . tgt_b) + mean_c sum_k logsig(-neg_bck . tgt_b) ]
//
// Memory-bound (gather). Vocab-range phasing: 3 launches, phase p handles only
// emb_out rows in [lo,hi) so the per-phase gather working set (~160 MB) fits
// the 256 MB Infinity Cache -> each unique row fetched from HBM exactly once
// (compulsory-only ~436 MB instead of 639 MB measured unphased).

#define D_DIM 300
#define D4    75     // float4 per row
#define C_DIM 10
#define NEG_DIM 50   // C*K
#define ROWS 60      // C + C*K
#define PHASES 3

__device__ __forceinline__ float log_sigmoid_fast(float x) {
    float e = __expf(-fabsf(x));
    return fminf(x, 0.f) - __logf(1.f + e);
}

__global__ __launch_bounds__(256) void w2v_loss_phase(
    const int*   __restrict__ target,
    const int*   __restrict__ context,
    const int*   __restrict__ negs,
    const float* __restrict__ emb_in,
    const float* __restrict__ emb_out,
    float*       __restrict__ partial,   // per-phase array, indexed by b
    int lo, int hi)
{
    const int tid  = threadIdx.x;
    const int lane = tid & 63;
    const int wave = tid >> 6;
    const int b    = blockIdx.x * 4 + wave;

    // lane r (<60) holds gather index of row r
    int v_idx = 0;
    if (lane < C_DIM)      v_idx = context[b * C_DIM + lane];
    else if (lane < ROWS)  v_idx = negs[b * NEG_DIM + (lane - C_DIM)];

    // target row in registers: lane j holds float4 j and (64+j)
    const float4* trow =
        reinterpret_cast<const float4*>(emb_in + (size_t)target[b] * D_DIM);
    const bool tail = lane < (D4 - 64);   // lanes 0..10
    float4 ta = trow[lane];
    float4 tb = make_float4(0.f, 0.f, 0.f, 0.f);
    if (tail) tb = trow[64 + lane];

    float acc = 0.f;
    for (int r = 0; r < ROWS; ++r) {
        const int sidx = __builtin_amdgcn_readlane(v_idx, r); // wave-uniform
        if (sidx >= lo && sidx < hi) {                        // scalar branch
            const float4* row =
                reinterpret_cast<const float4*>(emb_out + (size_t)sidx * D_DIM);
            float4 ra = row[lane];
            float4 rb = make_float4(0.f, 0.f, 0.f, 0.f);
            if (tail) rb = row[64 + lane];

            float dot = ra.x * ta.x + ra.y * ta.y + ra.z * ta.z + ra.w * ta.w
                      + rb.x * tb.x + rb.y * tb.y + rb.z * tb.z + rb.w * tb.w;
            #pragma unroll
            for (int off = 32; off > 0; off >>= 1)
                dot += __shfl_xor(dot, off, 64);

            const float x = (r < C_DIM) ? dot : -dot;
            acc += log_sigmoid_fast(x);   // replicated across lanes (hidden)
        }
    }

    if (lane == 0) partial[b] = acc;
}

__global__ __launch_bounds__(256) void w2v_loss_reduce(
    const float* __restrict__ partial,
    float*       __restrict__ out,
    int n, float inv_scale)
{
    __shared__ float s[256];
    float acc = 0.f;
    for (int i = threadIdx.x; i < n; i += 256) acc += partial[i];
    s[threadIdx.x] = acc;
    __syncthreads();
    #pragma unroll
    for (int off = 128; off > 0; off >>= 1) {
        if (threadIdx.x < off) s[threadIdx.x] += s[threadIdx.x + off];
        __syncthreads();
    }
    if (threadIdx.x == 0) out[0] = -s[0] * inv_scale;
}

extern "C" void kernel_launch(void* const* d_in, const int* in_sizes, int n_in,
                              void* d_out, int out_size, void* d_ws, size_t ws_size,
                              hipStream_t stream) {
    const int*   target  = (const int*)  d_in[0];
    const int*   context = (const int*)  d_in[1];
    const int*   negs    = (const int*)  d_in[2];
    const float* emb_in  = (const float*)d_in[3];
    const float* emb_out = (const float*)d_in[4];
    float*       out     = (float*)d_out;

    const int B = in_sizes[0];              // 16384
    const int V = in_sizes[3] / D_DIM;      // 400000
    float* partial = (float*)d_ws;          // PHASES * B floats

    for (int p = 0; p < PHASES; ++p) {
        const int lo = (int)((long long)V * p / PHASES);
        const int hi = (int)((long long)V * (p + 1) / PHASES);
        w2v_loss_phase<<<B / 4, 256, 0, stream>>>(target, context, negs,
                                                  emb_in, emb_out,
                                                  partial + (size_t)p * B,
                                                  lo, hi);
    }

    const float inv_scale = 1.0f / ((float)B * (float)C_DIM);
    w2v_loss_reduce<<<1, 256, 0, stream>>>(partial, out, PHASES * B, inv_scale);
}